// Round 1
// baseline (4990.727 us; speedup 1.0000x reference)
//
#include <hip/hip_runtime.h>

#define NN 20000
#define EE 640000
#define H 256
#define H3 768

typedef __attribute__((ext_vector_type(8))) short bfrag;   // 8 bf16 in 4 VGPRs
typedef __attribute__((ext_vector_type(4))) float f32x4;

__device__ __forceinline__ float silu_f(float x){ return x / (1.f + __expf(-x)); }

__device__ __forceinline__ short f2bf(float f){
  union { float fv; unsigned u; } a; a.fv = f;
  unsigned r = a.u + 0x7fffu + ((a.u >> 16) & 1u);   // RNE
  return (short)(r >> 16);
}

// ---------------- LayerNorm over H=256, one block per node ----------------
__global__ __launch_bounds__(256) void ln_kernel(
    const float* __restrict__ x, const float* __restrict__ w,
    const float* __restrict__ b, float* __restrict__ xn)
{
  int n = blockIdx.x, t = threadIdx.x;
  float v = x[(size_t)n*H + t];
  float s1 = v, s2 = v*v;
  #pragma unroll
  for(int o=32;o>0;o>>=1){ s1 += __shfl_down(s1,o,64); s2 += __shfl_down(s2,o,64); }
  __shared__ float r1[4], r2[4];
  if((t&63)==0){ r1[t>>6]=s1; r2[t>>6]=s2; }
  __syncthreads();
  float mu  = (r1[0]+r1[1]+r1[2]+r1[3]) * (1.f/256.f);
  float ex2 = (r2[0]+r2[1]+r2[2]+r2[3]) * (1.f/256.f);
  float inv = rsqrtf(ex2 - mu*mu + 1e-5f);
  xn[(size_t)n*H + t] = (v - mu)*inv*w[t] + b[t];
}

// ---- generic fp32 GEMM: C[M,ldw] = A[M,256] @ W[256,ldw] + bias ----
// 64x64 tile, BK=16, 256 threads, 4x4 micro-tile
__global__ __launch_bounds__(256) void gemm_f32(
    const float* __restrict__ A, const float* __restrict__ W, int ldw,
    const float* __restrict__ bias, float* __restrict__ C, int M)
{
  __shared__ float As[16][68];   // +4 pad: 16B-aligned float4 rows, no bank conflicts
  __shared__ float Bs[16][64];
  int tid = threadIdx.x;
  int m0 = blockIdx.x * 64;
  int n0 = blockIdx.y * 64;
  int tx = tid & 15, ty = tid >> 4;
  int arow = tid >> 2;
  int ak   = (tid & 3) * 4;
  int brow = tid >> 4;
  int bcol = (tid & 15) * 4;
  bool aval = (m0 + arow) < M;
  const float* Ap = A + (size_t)(m0 + arow) * 256;
  float acc[4][4] = {};
  for(int kb = 0; kb < 256; kb += 16){
    float4 av = make_float4(0.f,0.f,0.f,0.f);
    if(aval) av = *(const float4*)(Ap + kb + ak);
    As[ak+0][arow] = av.x; As[ak+1][arow] = av.y;
    As[ak+2][arow] = av.z; As[ak+3][arow] = av.w;
    *(float4*)&Bs[brow][bcol] = *(const float4*)(W + (size_t)(kb + brow)*ldw + n0 + bcol);
    __syncthreads();
    #pragma unroll
    for(int kk=0;kk<16;kk++){
      float4 a4 = *(const float4*)&As[kk][ty*4];
      float4 b4 = *(const float4*)&Bs[kk][tx*4];
      float aa[4] = {a4.x,a4.y,a4.z,a4.w};
      float bb[4] = {b4.x,b4.y,b4.z,b4.w};
      #pragma unroll
      for(int i=0;i<4;i++)
        #pragma unroll
        for(int j=0;j<4;j++)
          acc[i][j] += aa[i]*bb[j];
    }
    __syncthreads();
  }
  #pragma unroll
  for(int i=0;i<4;i++){
    int row = m0 + ty*4 + i;
    if(row < M){
      int col = n0 + tx*4;
      float4 o4;
      o4.x = acc[i][0] + (bias ? bias[col+0] : 0.f);
      o4.y = acc[i][1] + (bias ? bias[col+1] : 0.f);
      o4.z = acc[i][2] + (bias ? bias[col+2] : 0.f);
      o4.w = acc[i][3] + (bias ? bias[col+3] : 0.f);
      *(float4*)(C + (size_t)row*ldw + col) = o4;
    }
  }
}

// ---- vec_dot[n,c] = sum_d vp[3n+d][c] * vp[3n+d][256+c] ----
__global__ __launch_bounds__(256) void vecdot_kernel(
    const float* __restrict__ vp, float* __restrict__ vd)
{
  int i = blockIdx.x*256 + threadIdx.x;
  int n = i >> 8, c = i & 255;
  const float* base = vp + (size_t)(3*n)*H3;
  float s = 0.f;
  #pragma unroll
  for(int d=0;d<3;d++) s += base[d*H3 + c] * base[d*H3 + 256 + c];
  vd[i] = s;
}

// ---- fused edge kernel: dk/dv GEMM (bf16 MFMA) + attention + scatter ----
// 64 edges/block, 256 threads (4 waves, 16 edges/wave), all 1024 channels
__global__ __launch_bounds__(256) void edge_kernel(
    const int* __restrict__ ei, const float* __restrict__ rij,
    const float* __restrict__ fij, const float* __restrict__ dij,
    const float* __restrict__ qg, const float* __restrict__ kg,
    const float* __restrict__ vg, const float* __restrict__ vecg,
    const float* __restrict__ Wdk, const float* __restrict__ bdk,
    const float* __restrict__ Wdv, const float* __restrict__ bdv,
    float* __restrict__ xagg, float* __restrict__ dvec)
{
  __shared__ float f_lds[64][68];     // f tile, pad 68 -> conflict-free frag reads
  __shared__ short wb[16*1024];       // W in B-frag layout, 16 subtiles max (32KB)
  __shared__ float attn_lds[64][8];
  __shared__ int   src_lds[64];
  __shared__ int   dst_lds[64];
  __shared__ float cut_lds[64];
  __shared__ float dij_lds[64][3];

  int tid = threadIdx.x;
  int e0 = blockIdx.x * 64;

  if(tid < 64){
    int e = e0 + tid;
    src_lds[tid] = ei[e];
    dst_lds[tid] = ei[EE + e];
    float r = rij[e];
    float cu = 0.5f * (__cosf(r * 0.6283185307f) + 1.f);   // pi/5
    cut_lds[tid] = (r < 5.f) ? cu : 0.f;
    dij_lds[tid][0] = dij[e*3+0];
    dij_lds[tid][1] = dij[e*3+1];
    dij_lds[tid][2] = dij[e*3+2];
  }
  // stage f tile (64 edges x 64 rbf), coalesced float4
  #pragma unroll
  for(int it=0; it<4; it++){
    int fidx = it*256 + tid;
    int e = fidx >> 4, k4 = (fidx & 15) * 4;
    *(float4*)&f_lds[e][k4] = *(const float4*)(fij + (size_t)(e0+e)*64 + k4);
  }
  // stage Wdk (fp32 [64][256]) into bf16 B-frag layout: wb[s][hh][quad][n][j]
  #pragma unroll
  for(int it=0; it<16; it++){
    int idx4 = it*256 + tid;            // 4096 float4s
    int kk = idx4 >> 6, c4 = (idx4 & 63) * 4;
    float4 w4 = *(const float4*)(Wdk + (size_t)kk*H + c4);
    int hh = kk >> 5, qd = (kk >> 3) & 3, j = kk & 7;
    float wa[4] = {w4.x, w4.y, w4.z, w4.w};
    #pragma unroll
    for(int u=0;u<4;u++){
      int c = c4 + u;
      wb[(c>>4)*1024 + hh*512 + qd*128 + (c&15)*8 + j] = f2bf(wa[u]);
    }
  }
  __syncthreads();

  int wvid = tid >> 6;
  int lane = tid & 63;
  int ln15 = lane & 15, quad = lane >> 4;
  int ebase = wvid * 16;                // this wave's 16 edges

  // A fragments: A[m=ln15][k=quad*8+j], two K=32 halves
  bfrag af0, af1;
  {
    const float* fr = &f_lds[ebase + ln15][quad*8];
    #pragma unroll
    for(int j=0;j<8;j++) af0[j] = f2bf(fr[j]);
    #pragma unroll
    for(int j=0;j<8;j++) af1[j] = f2bf(fr[32+j]);
  }
  int dns[4], sns[4];
  #pragma unroll
  for(int r=0;r<4;r++){
    int el = ebase + quad*4 + r;        // C-frag row r -> edge
    dns[r] = dst_lds[el];
    sns[r] = src_lds[el];
  }

  // ---- dk + attention logits (16 col-subtiles = 256 dk channels) ----
  float lg[4] = {0.f,0.f,0.f,0.f};
  for(int s=0; s<16; s++){
    bfrag b0 = *(bfrag*)&wb[s*1024 +       quad*128 + ln15*8];
    bfrag b1 = *(bfrag*)&wb[s*1024 + 512 + quad*128 + ln15*8];
    f32x4 acc = {0.f,0.f,0.f,0.f};
    acc = __builtin_amdgcn_mfma_f32_16x16x32_bf16(af0, b0, acc, 0,0,0);
    acc = __builtin_amdgcn_mfma_f32_16x16x32_bf16(af1, b1, acc, 0,0,0);
    int c = s*16 + ln15;
    float bias = bdk[c];
    #pragma unroll
    for(int r=0;r<4;r++){
      float dk = silu_f(acc[r] + bias);
      float t = dk * qg[(size_t)dns[r]*H + c] * kg[(size_t)sns[r]*H + c];
      t += __shfl_xor(t, 1, 64);
      t += __shfl_xor(t, 2, 64);
      t += __shfl_xor(t, 4, 64);
      t += __shfl_xor(t, 8, 64);        // sum over 16 channels (n)
      lg[r] = (s & 1) ? (lg[r] + t) : t;
    }
    if((s & 1) && ln15 == 0){
      int h = s >> 1;
      #pragma unroll
      for(int r=0;r<4;r++) attn_lds[ebase + quad*4 + r][h] = lg[r];
    }
  }
  __syncthreads();
  {
    float* ap = &attn_lds[0][0];
    for(int i=tid; i<64*8; i+=256){
      ap[i] = silu_f(ap[i]) * cut_lds[i>>3];
    }
  }

  // ---- dv: 4 groups of 2 heads (12 subtiles each), reuse wb ----
  for(int hg=0; hg<4; hg++){
    __syncthreads();                    // everyone done reading previous wb
    #pragma unroll
    for(int it=0; it<12; it++){
      int idx4 = it*256 + tid;          // 3072 float4s
      int kk = idx4 / 48, c4 = (idx4 % 48) * 4;
      float4 w4 = *(const float4*)(Wdv + (size_t)kk*H3 + hg*192 + c4);
      int hh = kk >> 5, qd = (kk >> 3) & 3, j = kk & 7;
      float wa[4] = {w4.x, w4.y, w4.z, w4.w};
      #pragma unroll
      for(int u=0;u<4;u++){
        int c = c4 + u;
        wb[(c>>4)*1024 + hh*512 + qd*128 + (c&15)*8 + j] = f2bf(wa[u]);
      }
    }
    __syncthreads();

    #pragma unroll
    for(int h2=0; h2<2; h2++){
      int h = hg*2 + h2;
      int sb = h2*6;
      float v1[2][4];
      #pragma unroll
      for(int stype=0; stype<3; stype++){     // 0=xm, 1=v1m, 2=v2m
        #pragma unroll
        for(int p=0; p<2; p++){
          int ss = sb + stype*2 + p;
          bfrag b0 = *(bfrag*)&wb[ss*1024 +       quad*128 + ln15*8];
          bfrag b1 = *(bfrag*)&wb[ss*1024 + 512 + quad*128 + ln15*8];
          f32x4 acc = {0.f,0.f,0.f,0.f};
          acc = __builtin_amdgcn_mfma_f32_16x16x32_bf16(af0, b0, acc, 0,0,0);
          acc = __builtin_amdgcn_mfma_f32_16x16x32_bf16(af1, b1, acc, 0,0,0);
          int jj = stype*32 + p*16 + ln15;
          int cd = h*96 + jj;
          float bias = bdv[cd];
          #pragma unroll
          for(int r=0;r<4;r++){
            int el = ebase + quad*4 + r;
            float dvv = silu_f(acc[r] + bias);
            float vj = vg[(size_t)sns[r]*H3 + cd] * dvv;
            if(stype == 0){
              float val = vj * attn_lds[el][h];
              unsafeAtomicAdd(&xagg[(size_t)dns[r]*H + h*32 + p*16 + ln15], val);
            } else if(stype == 1){
              v1[p][r] = vj;
            } else {
              int hd = p*16 + ln15;
              #pragma unroll
              for(int d=0;d<3;d++){
                float contrib = vecg[(size_t)sns[r]*H3 + d*H + h*32 + hd] * v1[p][r]
                              + dij_lds[el][d] * vj;
                unsafeAtomicAdd(&dvec[(size_t)dns[r]*H3 + d*H + h*32 + hd], contrib);
              }
            }
          }
        }
      }
    }
  }
}

// ---- epilogue: dx = vec_dot*o2 + o3 ; dvec += vec3*o1 ----
__global__ __launch_bounds__(256) void final_kernel(
    const float* __restrict__ ob, const float* __restrict__ vd,
    const float* __restrict__ vp, float* __restrict__ out)
{
  int i = blockIdx.x*256 + threadIdx.x;
  int n = i >> 8, c = i & 255;
  float o1 = ob[(size_t)n*H3 + c];
  float o2 = ob[(size_t)n*H3 + 256 + c];
  float o3 = ob[(size_t)n*H3 + 512 + c];
  out[i] = vd[i]*o2 + o3;
  float* dvec = out + (size_t)NN*H;
  const float* v3 = vp + (size_t)(3*n)*H3 + 512;
  #pragma unroll
  for(int d=0;d<3;d++){
    dvec[(size_t)n*H3 + d*H + c] += v3[d*H3 + c] * o1;
  }
}

extern "C" void kernel_launch(void* const* d_in, const int* in_sizes, int n_in,
                              void* d_out, int out_size, void* d_ws, size_t ws_size,
                              hipStream_t stream){
  (void)in_sizes; (void)n_in; (void)out_size; (void)ws_size;
  const float* x    = (const float*)d_in[0];
  const float* vec  = (const float*)d_in[1];
  const int*   ei   = (const int*)d_in[2];
  const float* rij  = (const float*)d_in[3];
  const float* fij  = (const float*)d_in[4];
  const float* dij  = (const float*)d_in[5];
  const float* ln_w = (const float*)d_in[6];
  const float* ln_b = (const float*)d_in[7];
  const float* Wq   = (const float*)d_in[8];
  const float* bq   = (const float*)d_in[9];
  const float* Wk   = (const float*)d_in[10];
  const float* bk   = (const float*)d_in[11];
  const float* Wv   = (const float*)d_in[12];
  const float* bv   = (const float*)d_in[13];
  const float* Wo   = (const float*)d_in[14];
  const float* bo   = (const float*)d_in[15];
  const float* Wvec = (const float*)d_in[16];
  const float* Wdk  = (const float*)d_in[17];
  const float* bdk  = (const float*)d_in[18];
  const float* Wdv  = (const float*)d_in[19];
  const float* bdv  = (const float*)d_in[20];
  float* out = (float*)d_out;
  float* ws  = (float*)d_ws;

  // workspace layout (floats): total 87,040,000 = 348.2 MB
  float* xn   = ws;                 // [N,256]
  float* qb   = ws + 5120000;       // [N,256]
  float* kb   = ws + 10240000;      // [N,256]
  float* vb   = ws + 15360000;      // [N,768]
  float* vp   = ws + 30720000;      // [3N,768] vec_proj
  float* vd   = ws + 76800000;      // [N,256] vec_dot
  float* xagg = ws + 81920000;      // [N,256]
  float* dvec = out + 5120000;      // [N,3,256] region of d_out
  float* ob   = vb;                 // o reuses v region (v dead after edge_kernel)

  hipMemsetAsync(xagg, 0, 20480000, stream);
  hipMemsetAsync(dvec, 0, 61440000, stream);

  ln_kernel<<<20000, 256, 0, stream>>>(x, ln_w, ln_b, xn);
  gemm_f32<<<dim3(313,4),  256, 0, stream>>>(xn,  Wq,   256, bq,      qb, 20000);
  gemm_f32<<<dim3(313,4),  256, 0, stream>>>(xn,  Wk,   256, bk,      kb, 20000);
  gemm_f32<<<dim3(313,12), 256, 0, stream>>>(xn,  Wv,   768, bv,      vb, 20000);
  gemm_f32<<<dim3(938,12), 256, 0, stream>>>(vec, Wvec, 768, nullptr, vp, 60000);
  vecdot_kernel<<<20000, 256, 0, stream>>>(vp, vd);
  edge_kernel<<<10000, 256, 0, stream>>>(ei, rij, fij, dij, qb, kb, vb, vec,
                                         Wdk, bdk, Wdv, bdv, xagg, dvec);
  gemm_f32<<<dim3(313,12), 256, 0, stream>>>(xagg, Wo, 768, bo, ob, 20000);
  final_kernel<<<20000, 256, 0, stream>>>(ob, vd, vp, out);
}

// Round 2
// 2946.958 us; speedup vs baseline: 1.6935x; 1.6935x over previous
//
#include <hip/hip_runtime.h>

#define NN 20000
#define EE 640000
#define H 256
#define H3 768

typedef __attribute__((ext_vector_type(8))) short bfrag;   // 8 bf16 in 4 VGPRs
typedef __attribute__((ext_vector_type(4))) float f32x4;

__device__ __forceinline__ float silu_f(float x){ return x / (1.f + __expf(-x)); }

__device__ __forceinline__ short f2bf(float f){
  union { float fv; unsigned u; } a; a.fv = f;
  unsigned r = a.u + 0x7fffu + ((a.u >> 16) & 1u);   // RNE
  return (short)(r >> 16);
}

// ---------------- LayerNorm over H=256, one block per node ----------------
__global__ __launch_bounds__(256) void ln_kernel(
    const float* __restrict__ x, const float* __restrict__ w,
    const float* __restrict__ b, float* __restrict__ xn)
{
  int n = blockIdx.x, t = threadIdx.x;
  float v = x[(size_t)n*H + t];
  float s1 = v, s2 = v*v;
  #pragma unroll
  for(int o=32;o>0;o>>=1){ s1 += __shfl_down(s1,o,64); s2 += __shfl_down(s2,o,64); }
  __shared__ float r1[4], r2[4];
  if((t&63)==0){ r1[t>>6]=s1; r2[t>>6]=s2; }
  __syncthreads();
  float mu  = (r1[0]+r1[1]+r1[2]+r1[3]) * (1.f/256.f);
  float ex2 = (r2[0]+r2[1]+r2[2]+r2[3]) * (1.f/256.f);
  float inv = rsqrtf(ex2 - mu*mu + 1e-5f);
  xn[(size_t)n*H + t] = (v - mu)*inv*w[t] + b[t];
}

// ---- generic fp32 GEMM: C[M,ldw] = A[M,256] @ W[256,ldw] + bias ----
__global__ __launch_bounds__(256) void gemm_f32(
    const float* __restrict__ A, const float* __restrict__ W, int ldw,
    const float* __restrict__ bias, float* __restrict__ C, int M)
{
  __shared__ float As[16][68];
  __shared__ float Bs[16][64];
  int tid = threadIdx.x;
  int m0 = blockIdx.x * 64;
  int n0 = blockIdx.y * 64;
  int tx = tid & 15, ty = tid >> 4;
  int arow = tid >> 2;
  int ak   = (tid & 3) * 4;
  int brow = tid >> 4;
  int bcol = (tid & 15) * 4;
  bool aval = (m0 + arow) < M;
  const float* Ap = A + (size_t)(m0 + arow) * 256;
  float acc[4][4] = {};
  for(int kb = 0; kb < 256; kb += 16){
    float4 av = make_float4(0.f,0.f,0.f,0.f);
    if(aval) av = *(const float4*)(Ap + kb + ak);
    As[ak+0][arow] = av.x; As[ak+1][arow] = av.y;
    As[ak+2][arow] = av.z; As[ak+3][arow] = av.w;
    *(float4*)&Bs[brow][bcol] = *(const float4*)(W + (size_t)(kb + brow)*ldw + n0 + bcol);
    __syncthreads();
    #pragma unroll
    for(int kk=0;kk<16;kk++){
      float4 a4 = *(const float4*)&As[kk][ty*4];
      float4 b4 = *(const float4*)&Bs[kk][tx*4];
      float aa[4] = {a4.x,a4.y,a4.z,a4.w};
      float bb[4] = {b4.x,b4.y,b4.z,b4.w};
      #pragma unroll
      for(int i=0;i<4;i++)
        #pragma unroll
        for(int j=0;j<4;j++)
          acc[i][j] += aa[i]*bb[j];
    }
    __syncthreads();
  }
  #pragma unroll
  for(int i=0;i<4;i++){
    int row = m0 + ty*4 + i;
    if(row < M){
      int col = n0 + tx*4;
      float4 o4;
      o4.x = acc[i][0] + (bias ? bias[col+0] : 0.f);
      o4.y = acc[i][1] + (bias ? bias[col+1] : 0.f);
      o4.z = acc[i][2] + (bias ? bias[col+2] : 0.f);
      o4.w = acc[i][3] + (bias ? bias[col+3] : 0.f);
      *(float4*)(C + (size_t)row*ldw + col) = o4;
    }
  }
}

// ---- vec_dot ----
__global__ __launch_bounds__(256) void vecdot_kernel(
    const float* __restrict__ vp, float* __restrict__ vd)
{
  int i = blockIdx.x*256 + threadIdx.x;
  int n = i >> 8, c = i & 255;
  const float* base = vp + (size_t)(3*n)*H3;
  float s = 0.f;
  #pragma unroll
  for(int d=0;d<3;d++) s += base[d*H3 + c] * base[d*H3 + 256 + c];
  vd[i] = s;
}

// ---------------- CSR build ----------------
__global__ __launch_bounds__(256) void hist_kernel(const int* __restrict__ ei, int* __restrict__ deg){
  int e = blockIdx.x*256 + threadIdx.x;
  if(e < EE) atomicAdd(&deg[ei[EE + e]], 1);
}

__global__ __launch_bounds__(1024) void scan_kernel(const int* __restrict__ deg, int* __restrict__ offs){
  __shared__ int ps[1024];
  int t = threadIdx.x;
  int base = t*20;
  int s = 0;
  for(int i=0;i<20;i++){ int idx = base+i; if(idx < NN) s += deg[idx]; }
  ps[t] = s; __syncthreads();
  for(int off=1; off<1024; off<<=1){
    int v = (t>=off) ? ps[t-off] : 0;
    __syncthreads();
    ps[t] += v;
    __syncthreads();
  }
  int run = (t==0) ? 0 : ps[t-1];
  for(int i=0;i<20;i++){
    int idx = base+i;
    if(idx <= NN){
      offs[idx] = run;
      if(idx < NN) run += deg[idx];
    }
  }
}

__global__ __launch_bounds__(256) void scatter_kernel(
    const int* __restrict__ ei, const int* __restrict__ offs,
    int* __restrict__ cursor, int* __restrict__ perm)
{
  int e = blockIdx.x*256 + threadIdx.x;
  if(e >= EE) return;
  int d = ei[EE + e];
  int r = atomicAdd(&cursor[d], 1);
  perm[offs[d] + r] = e;
}

// ---------------- weight -> bf16 B-fragment layout ----------------
__global__ __launch_bounds__(256) void conv_wdk(const float* __restrict__ Wdk, short* __restrict__ wdkf){
  int idx = blockIdx.x*256 + threadIdx.x;      // 64*256 = 16384
  int k = idx >> 8, c = idx & 255;
  short v = f2bf(Wdk[k*H + c]);
  int s = c >> 4, n15 = c & 15, half = k >> 5, quad = (k >> 3) & 3, j = k & 7;
  wdkf[s*1024 + half*512 + quad*128 + n15*8 + j] = v;
}

__global__ __launch_bounds__(256) void conv_wdv(const float* __restrict__ Wdv, short* __restrict__ wdvf){
  int idx = blockIdx.x*256 + threadIdx.x;      // 64*768 = 49152
  int k = idx / 768, c = idx % 768;
  short v = f2bf(Wdv[k*H3 + c]);
  int h = c / 96, jj = c % 96;
  int stype = jj >> 5, rest = jj & 31, p = rest >> 4, n15 = rest & 15;
  int sub = h*6 + stype*2 + p;
  int half = k >> 5, quad = (k >> 3) & 3, j = k & 7;
  wdvf[sub*1024 + half*512 + quad*128 + n15*8 + j] = v;
}

// ---------------- edge kernel: one wave per dst node, zero atomics ----------------
__global__ __launch_bounds__(256,3) void edge_kernel(
    const int* __restrict__ ei, const float* __restrict__ rij,
    const float* __restrict__ fij, const float* __restrict__ dij,
    const float* __restrict__ qg, const float* __restrict__ kg,
    const float* __restrict__ vg, const float* __restrict__ vecg,
    const short* __restrict__ wdkf, const short* __restrict__ wdvf,
    const float* __restrict__ bdk, const float* __restrict__ bdv,
    const int* __restrict__ offs, const int* __restrict__ perm,
    float* __restrict__ xagg, float* __restrict__ dvec)
{
  __shared__ float attn_s[4][16][8];
  __shared__ int   esrc_s[4][16];
  __shared__ float ecut_s[4][16];
  __shared__ float emask_s[4][16];
  __shared__ float edij_s[4][3][16];
  __shared__ float accs_x[4][256];
  __shared__ float accs_v[4][768];

  int tid  = threadIdx.x;
  int wv   = tid >> 6, lane = tid & 63;
  int ln15 = lane & 15, quad = lane >> 4;
  int n    = blockIdx.x*4 + wv;
  int rs = offs[n], re = offs[n+1];

  // zero per-wave accumulators (same-wave only -> no barrier needed)
  #pragma unroll
  for(int i=0;i<4;i++)  accs_x[wv][i*64 + lane] = 0.f;
  #pragma unroll
  for(int i=0;i<12;i++) accs_v[wv][i*64 + lane] = 0.f;

  for(int base = rs; base < re; base += 16){
    int idx = base + ln15;
    bool val = idx < re;
    int e = perm[val ? idx : rs];
    if(quad == 0){
      esrc_s[wv][ln15] = ei[e];
      float r = rij[e];
      float cu = 0.5f*(__cosf(r*0.6283185307f)+1.f);
      cu = (r < 5.f) ? cu : 0.f;
      ecut_s[wv][ln15]  = val ? cu : 0.f;
      emask_s[wv][ln15] = val ? 1.f : 0.f;
      edij_s[wv][0][ln15] = dij[e*3+0];
      edij_s[wv][1][ln15] = dij[e*3+1];
      edij_s[wv][2][ln15] = dij[e*3+2];
    }
    // A fragments from f_ij (row = this lane's ln15 edge, k = quad*8..)
    bfrag af0, af1;
    {
      const float* fr = fij + (size_t)e*64 + quad*8;
      float a0[8], a1[8];
      *(float4*)&a0[0] = *(const float4*)(fr);
      *(float4*)&a0[4] = *(const float4*)(fr+4);
      *(float4*)&a1[0] = *(const float4*)(fr+32);
      *(float4*)&a1[4] = *(const float4*)(fr+36);
      #pragma unroll
      for(int j=0;j<8;j++){
        af0[j] = val ? f2bf(a0[j]) : (short)0;
        af1[j] = val ? f2bf(a1[j]) : (short)0;
      }
    }
    int sns[4]; float mk[4];
    #pragma unroll
    for(int r=0;r<4;r++){
      int el = quad*4 + r;
      sns[r] = esrc_s[wv][el];
      mk[r]  = emask_s[wv][el];
    }

    // ---- dk + attention logits ----
    #pragma unroll 2
    for(int h=0; h<8; h++){
      float lg[4] = {0.f,0.f,0.f,0.f};
      #pragma unroll
      for(int hf=0; hf<2; hf++){
        int s = h*2 + hf;
        const short* wp = wdkf + s*1024 + quad*128 + ln15*8;
        bfrag b0 = *(const bfrag*)wp;
        bfrag b1 = *(const bfrag*)(wp + 512);
        f32x4 acc = {0.f,0.f,0.f,0.f};
        acc = __builtin_amdgcn_mfma_f32_16x16x32_bf16(af0, b0, acc, 0,0,0);
        acc = __builtin_amdgcn_mfma_f32_16x16x32_bf16(af1, b1, acc, 0,0,0);
        int c = s*16 + ln15;
        float bias = bdk[c];
        float qv = qg[(size_t)n*H + c];
        #pragma unroll
        for(int r=0;r<4;r++){
          float dk = silu_f(acc[r] + bias);
          float t = dk * qv * kg[(size_t)sns[r]*H + c];
          t += __shfl_xor(t,1,64); t += __shfl_xor(t,2,64);
          t += __shfl_xor(t,4,64); t += __shfl_xor(t,8,64);
          lg[r] += t;
        }
      }
      if(ln15 == 0){
        #pragma unroll
        for(int r=0;r<4;r++) attn_s[wv][quad*4+r][h] = lg[r];
      }
    }
    // silu * cutoff (same wave, no barrier)
    #pragma unroll
    for(int i=0;i<2;i++){
      int ii = i*64 + lane;
      int ee = ii >> 3, hh = ii & 7;
      float a = attn_s[wv][ee][hh];
      attn_s[wv][ee][hh] = silu_f(a) * ecut_s[wv][ee];
    }

    // ---- dv + accumulate ----
    #pragma unroll 1
    for(int h=0; h<8; h++){
      float at[4];
      #pragma unroll
      for(int r=0;r<4;r++) at[r] = attn_s[wv][quad*4+r][h];
      float v1[2][4];
      #pragma unroll
      for(int p=0;p<2;p++){      // stype 0 (xm) and stype 1 (v1m) first
        {
          int sub = h*6 + 0*2 + p;
          const short* wp = wdvf + sub*1024 + quad*128 + ln15*8;
          bfrag b0 = *(const bfrag*)wp;
          bfrag b1 = *(const bfrag*)(wp + 512);
          f32x4 acc = {0.f,0.f,0.f,0.f};
          acc = __builtin_amdgcn_mfma_f32_16x16x32_bf16(af0, b0, acc, 0,0,0);
          acc = __builtin_amdgcn_mfma_f32_16x16x32_bf16(af1, b1, acc, 0,0,0);
          int cd = h*96 + 0*32 + p*16 + ln15;
          float bias = bdv[cd];
          float t = 0.f;
          #pragma unroll
          for(int r=0;r<4;r++){
            float dvv = silu_f(acc[r] + bias) * mk[r];
            float vj = vg[(size_t)sns[r]*H3 + cd] * dvv;
            t += vj * at[r];
          }
          t += __shfl_xor(t,16,64); t += __shfl_xor(t,32,64);
          if(quad == 0) accs_x[wv][h*32 + p*16 + ln15] += t;
        }
        {
          int sub = h*6 + 1*2 + p;
          const short* wp = wdvf + sub*1024 + quad*128 + ln15*8;
          bfrag b0 = *(const bfrag*)wp;
          bfrag b1 = *(const bfrag*)(wp + 512);
          f32x4 acc = {0.f,0.f,0.f,0.f};
          acc = __builtin_amdgcn_mfma_f32_16x16x32_bf16(af0, b0, acc, 0,0,0);
          acc = __builtin_amdgcn_mfma_f32_16x16x32_bf16(af1, b1, acc, 0,0,0);
          int cd = h*96 + 1*32 + p*16 + ln15;
          float bias = bdv[cd];
          #pragma unroll
          for(int r=0;r<4;r++){
            float dvv = silu_f(acc[r] + bias) * mk[r];
            v1[p][r] = vg[(size_t)sns[r]*H3 + cd] * dvv;
          }
        }
      }
      #pragma unroll
      for(int p=0;p<2;p++){      // stype 2 (v2m) + vecm accumulate
        int sub = h*6 + 2*2 + p;
        const short* wp = wdvf + sub*1024 + quad*128 + ln15*8;
        bfrag b0 = *(const bfrag*)wp;
        bfrag b1 = *(const bfrag*)(wp + 512);
        f32x4 acc = {0.f,0.f,0.f,0.f};
        acc = __builtin_amdgcn_mfma_f32_16x16x32_bf16(af0, b0, acc, 0,0,0);
        acc = __builtin_amdgcn_mfma_f32_16x16x32_bf16(af1, b1, acc, 0,0,0);
        int cd = h*96 + 2*32 + p*16 + ln15;
        float bias = bdv[cd];
        float vj[4];
        #pragma unroll
        for(int r=0;r<4;r++){
          float dvv = silu_f(acc[r] + bias) * mk[r];
          vj[r] = vg[(size_t)sns[r]*H3 + cd] * dvv;
        }
        #pragma unroll
        for(int d=0;d<3;d++){
          float t = 0.f;
          #pragma unroll
          for(int r=0;r<4;r++){
            t += vecg[(size_t)sns[r]*H3 + d*H + h*32 + p*16 + ln15] * v1[p][r]
               + edij_s[wv][d][quad*4+r] * vj[r];
          }
          t += __shfl_xor(t,16,64); t += __shfl_xor(t,32,64);
          if(quad == 0) accs_v[wv][d*H + h*32 + p*16 + ln15] += t;
        }
      }
    }
  }

  // write out (one wave owns node n exclusively)
  #pragma unroll
  for(int j=0;j<4;j++)  xagg[(size_t)n*H  + j*64 + lane] = accs_x[wv][j*64 + lane];
  #pragma unroll
  for(int j=0;j<12;j++) dvec[(size_t)n*H3 + j*64 + lane] = accs_v[wv][j*64 + lane];
}

// ---- epilogue ----
__global__ __launch_bounds__(256) void final_kernel(
    const float* __restrict__ ob, const float* __restrict__ vd,
    const float* __restrict__ vp, float* __restrict__ out)
{
  int i = blockIdx.x*256 + threadIdx.x;
  int n = i >> 8, c = i & 255;
  float o1 = ob[(size_t)n*H3 + c];
  float o2 = ob[(size_t)n*H3 + 256 + c];
  float o3 = ob[(size_t)n*H3 + 512 + c];
  out[i] = vd[i]*o2 + o3;
  float* dvec = out + (size_t)NN*H;
  const float* v3 = vp + (size_t)(3*n)*H3 + 512;
  #pragma unroll
  for(int d=0;d<3;d++){
    dvec[(size_t)n*H3 + d*H + c] += v3[d*H3 + c] * o1;
  }
}

extern "C" void kernel_launch(void* const* d_in, const int* in_sizes, int n_in,
                              void* d_out, int out_size, void* d_ws, size_t ws_size,
                              hipStream_t stream){
  (void)in_sizes; (void)n_in; (void)out_size; (void)ws_size;
  const float* x    = (const float*)d_in[0];
  const float* vec  = (const float*)d_in[1];
  const int*   ei   = (const int*)d_in[2];
  const float* rij  = (const float*)d_in[3];
  const float* fij  = (const float*)d_in[4];
  const float* dij  = (const float*)d_in[5];
  const float* ln_w = (const float*)d_in[6];
  const float* ln_b = (const float*)d_in[7];
  const float* Wq   = (const float*)d_in[8];
  const float* bq   = (const float*)d_in[9];
  const float* Wk   = (const float*)d_in[10];
  const float* bk   = (const float*)d_in[11];
  const float* Wv   = (const float*)d_in[12];
  const float* bv   = (const float*)d_in[13];
  const float* Wo   = (const float*)d_in[14];
  const float* bo   = (const float*)d_in[15];
  const float* Wvec = (const float*)d_in[16];
  const float* Wdk  = (const float*)d_in[17];
  const float* bdk  = (const float*)d_in[18];
  const float* Wdv  = (const float*)d_in[19];
  const float* bdv  = (const float*)d_in[20];
  float* out = (float*)d_out;
  float* ws  = (float*)d_ws;

  // workspace layout (floats)
  float* xn   = ws;                 // [N,256]   (reused for CSR after q/k/v gemms)
  float* qb   = ws + 5120000;       // [N,256]
  float* kb   = ws + 10240000;      // [N,256]
  float* vb   = ws + 15360000;      // [N,768]
  float* vp   = ws + 30720000;      // [3N,768]
  float* vd   = ws + 76800000;      // [N,256]
  float* xagg = ws + 81920000;      // [N,256]
  float* dvec = out + 5120000;      // [N,3,256] region of d_out
  float* ob   = vb;                 // Wo output reuses v region

  // CSR + frag-weights carved out of the xn region (xn dead after q/k/v gemms)
  int* deg    = (int*)xn;           // 20000
  int* offs   = deg + 20032;        // 20001
  int* cursor = offs + 20032;       // 20000
  int* perm   = cursor + 20032;     // 640000
  short* wdkf = (short*)(perm + 640000);   // 16384 shorts
  short* wdvf = wdkf + 16384;              // 49152 shorts

  ln_kernel<<<20000, 256, 0, stream>>>(x, ln_w, ln_b, xn);
  gemm_f32<<<dim3(313,4),  256, 0, stream>>>(xn,  Wq,   256, bq,      qb, 20000);
  gemm_f32<<<dim3(313,4),  256, 0, stream>>>(xn,  Wk,   256, bk,      kb, 20000);
  gemm_f32<<<dim3(313,12), 256, 0, stream>>>(xn,  Wv,   768, bv,      vb, 20000);

  // CSR build (xn region now reusable)
  hipMemsetAsync(deg,    0, 20000*sizeof(int), stream);
  hipMemsetAsync(cursor, 0, 20000*sizeof(int), stream);
  hist_kernel<<<2500, 256, 0, stream>>>(ei, deg);
  scan_kernel<<<1, 1024, 0, stream>>>(deg, offs);
  scatter_kernel<<<2500, 256, 0, stream>>>(ei, offs, cursor, perm);
  conv_wdk<<<64,  256, 0, stream>>>(Wdk, wdkf);
  conv_wdv<<<192, 256, 0, stream>>>(Wdv, wdvf);

  gemm_f32<<<dim3(938,12), 256, 0, stream>>>(vec, Wvec, 768, nullptr, vp, 60000);
  vecdot_kernel<<<20000, 256, 0, stream>>>(vp, vd);

  edge_kernel<<<5000, 256, 0, stream>>>(ei, rij, fij, dij, qb, kb, vb, vec,
                                        wdkf, wdvf, bdk, bdv, offs, perm,
                                        xagg, dvec);

  gemm_f32<<<dim3(313,12), 256, 0, stream>>>(xagg, Wo, 768, bo, ob, 20000);
  final_kernel<<<20000, 256, 0, stream>>>(ob, vd, vp, out);
}

// Round 3
// 2376.023 us; speedup vs baseline: 2.1005x; 1.2403x over previous
//
#include <hip/hip_runtime.h>

#define NN 20000
#define EE 640000
#define H 256
#define H3 768

typedef __attribute__((ext_vector_type(8))) short bfrag;
typedef __attribute__((ext_vector_type(4))) float f32x4;
typedef __attribute__((ext_vector_type(2))) unsigned short u16x2;
typedef __attribute__((ext_vector_type(4))) unsigned short u16x4;
typedef unsigned short u16;

__device__ __forceinline__ float silu_f(float x){ return x / (1.f + __expf(-x)); }

__device__ __forceinline__ u16 f2bf(float f){
  union { float fv; unsigned u; } a; a.fv = f;
  unsigned r = a.u + 0x7fffu + ((a.u >> 16) & 1u);   // RNE
  return (u16)(r >> 16);
}
__device__ __forceinline__ float bf2f(u16 u){
  union { unsigned u32; float f; } a; a.u32 = ((unsigned)u) << 16; return a.f;
}

// ---------------- LayerNorm ----------------
__global__ __launch_bounds__(256) void ln_kernel(
    const float* __restrict__ x, const float* __restrict__ w,
    const float* __restrict__ b, float* __restrict__ xn)
{
  int n = blockIdx.x, t = threadIdx.x;
  float v = x[(size_t)n*H + t];
  float s1 = v, s2 = v*v;
  #pragma unroll
  for(int o=32;o>0;o>>=1){ s1 += __shfl_down(s1,o,64); s2 += __shfl_down(s2,o,64); }
  __shared__ float r1[4], r2[4];
  if((t&63)==0){ r1[t>>6]=s1; r2[t>>6]=s2; }
  __syncthreads();
  float mu  = (r1[0]+r1[1]+r1[2]+r1[3]) * (1.f/256.f);
  float ex2 = (r2[0]+r2[1]+r2[2]+r2[3]) * (1.f/256.f);
  float inv = rsqrtf(ex2 - mu*mu + 1e-5f);
  xn[(size_t)n*H + t] = (v - mu)*inv*w[t] + b[t];
}

// ---- node GEMM: C[M,ldw] = A[M,256] @ W[256,ldw] + bias ----
// MODE 0: fp32 out; MODE 1: bf16 out; MODE 2: fp32 split into 3 bufs of [M,256]
template<int MODE>
__global__ __launch_bounds__(256) void gemm_node(
    const float* __restrict__ A, const float* __restrict__ W, int ldw,
    const float* __restrict__ bias, float* __restrict__ C,
    u16* __restrict__ Ch, long bufstride, int M)
{
  __shared__ float As[16][68];
  __shared__ float Bs[16][64];
  int tid = threadIdx.x;
  int m0 = blockIdx.x * 64;
  int n0 = blockIdx.y * 64;
  int tx = tid & 15, ty = tid >> 4;
  int arow = tid >> 2;
  int ak   = (tid & 3) * 4;
  int brow = tid >> 4;
  int bcol = (tid & 15) * 4;
  bool aval = (m0 + arow) < M;
  const float* Ap = A + (size_t)(m0 + arow) * 256;
  float acc[4][4] = {};
  for(int kb = 0; kb < 256; kb += 16){
    float4 av = make_float4(0.f,0.f,0.f,0.f);
    if(aval) av = *(const float4*)(Ap + kb + ak);
    As[ak+0][arow] = av.x; As[ak+1][arow] = av.y;
    As[ak+2][arow] = av.z; As[ak+3][arow] = av.w;
    *(float4*)&Bs[brow][bcol] = *(const float4*)(W + (size_t)(kb + brow)*ldw + n0 + bcol);
    __syncthreads();
    #pragma unroll
    for(int kk=0;kk<16;kk++){
      float4 a4 = *(const float4*)&As[kk][ty*4];
      float4 b4 = *(const float4*)&Bs[kk][tx*4];
      float aa[4] = {a4.x,a4.y,a4.z,a4.w};
      float bb[4] = {b4.x,b4.y,b4.z,b4.w};
      #pragma unroll
      for(int i=0;i<4;i++)
        #pragma unroll
        for(int j=0;j<4;j++)
          acc[i][j] += aa[i]*bb[j];
    }
    __syncthreads();
  }
  #pragma unroll
  for(int i=0;i<4;i++){
    int row = m0 + ty*4 + i;
    if(row < M){
      int col = n0 + tx*4;
      float o[4];
      #pragma unroll
      for(int j=0;j<4;j++) o[j] = acc[i][j] + (bias ? bias[col+j] : 0.f);
      if(MODE == 0){
        *(float4*)(C + (size_t)row*ldw + col) = make_float4(o[0],o[1],o[2],o[3]);
      } else if(MODE == 1){
        u16x4 h; h[0]=f2bf(o[0]); h[1]=f2bf(o[1]); h[2]=f2bf(o[2]); h[3]=f2bf(o[3]);
        *(u16x4*)(Ch + (size_t)row*ldw + col) = h;
      } else {
        int buf = n0 >> 8;
        int coff = (n0 & 255) + tx*4;
        *(float4*)(C + (size_t)buf*bufstride + (size_t)row*256 + coff)
            = make_float4(o[0],o[1],o[2],o[3]);
      }
    }
  }
}

// ---- vec_dot from split buffers ----
__global__ __launch_bounds__(256) void vecdot_kernel(
    const float* __restrict__ vp1, const float* __restrict__ vp2, float* __restrict__ vd)
{
  int i = blockIdx.x*256 + threadIdx.x;
  int n = i >> 8, c = i & 255;
  size_t base = (size_t)(3*n)*256 + c;
  float s = 0.f;
  #pragma unroll
  for(int d=0;d<3;d++) s += vp1[base + d*256] * vp2[base + d*256];
  vd[i] = s;
}

// ---- fp32 -> bf16 convert (count must be multiple of 4) ----
__global__ __launch_bounds__(256) void cvt_bf16(
    const float* __restrict__ src, u16* __restrict__ dst, int n4)
{
  int i = blockIdx.x*256 + threadIdx.x;
  if(i < n4){
    float4 v = ((const float4*)src)[i];
    u16x4 o; o[0]=f2bf(v.x); o[1]=f2bf(v.y); o[2]=f2bf(v.z); o[3]=f2bf(v.w);
    ((u16x4*)dst)[i] = o;
  }
}

// ---------------- CSR build ----------------
__global__ __launch_bounds__(256) void hist_kernel(const int* __restrict__ ei, int* __restrict__ deg){
  int e = blockIdx.x*256 + threadIdx.x;
  if(e < EE) atomicAdd(&deg[ei[EE + e]], 1);
}

__global__ __launch_bounds__(1024) void scan_kernel(const int* __restrict__ deg, int* __restrict__ offs){
  __shared__ int ps[1024];
  int t = threadIdx.x;
  int base = t*20;
  int s = 0;
  for(int i=0;i<20;i++){ int idx = base+i; if(idx < NN) s += deg[idx]; }
  ps[t] = s; __syncthreads();
  for(int off=1; off<1024; off<<=1){
    int v = (t>=off) ? ps[t-off] : 0;
    __syncthreads();
    ps[t] += v;
    __syncthreads();
  }
  int run = (t==0) ? 0 : ps[t-1];
  for(int i=0;i<20;i++){
    int idx = base+i;
    if(idx <= NN){
      offs[idx] = run;
      if(idx < NN) run += deg[idx];
    }
  }
}

__global__ __launch_bounds__(256) void scatter_kernel(
    const int* __restrict__ ei, const int* __restrict__ offs,
    int* __restrict__ cursor, int* __restrict__ perm)
{
  int e = blockIdx.x*256 + threadIdx.x;
  if(e >= EE) return;
  int d = ei[EE + e];
  int r = atomicAdd(&cursor[d], 1);
  perm[offs[d] + r] = e;
}

// ---------------- weight -> bf16 B-fragment layout (channel-interleaved) ----------------
// dk subtile (g,p): col n15 <-> channel c = g*64 + 4*n15 + p
__global__ __launch_bounds__(256) void conv_wdk(const float* __restrict__ Wdk, short* __restrict__ wdkf){
  int idx = blockIdx.x*256 + threadIdx.x;      // 64*256
  int k = idx >> 8, c = idx & 255;
  int g = c >> 6, rem = c & 63, n15 = rem >> 2, p = rem & 3;
  int half = k >> 5, quad = (k >> 3) & 3, j = k & 7;
  wdkf[(g*4+p)*1024 + half*512 + quad*128 + n15*8 + j] = (short)f2bf(Wdk[k*H + c]);
}

// dv subtile (h,st,p): col n15 <-> channel c = h*96 + st*32 + 2*n15 + p
__global__ __launch_bounds__(256) void conv_wdv(const float* __restrict__ Wdv, short* __restrict__ wdvf){
  int idx = blockIdx.x*256 + threadIdx.x;      // 64*768
  int k = idx / 768, c = idx % 768;
  int h = c / 96, jj = c % 96;
  int st = jj >> 5, r32 = jj & 31, n15 = r32 >> 1, p = r32 & 1;
  int sub = h*6 + st*2 + p;
  int half = k >> 5, quad = (k >> 3) & 3, j = k & 7;
  wdvf[sub*1024 + half*512 + quad*128 + n15*8 + j] = (short)f2bf(Wdv[k*H3 + c]);
}

// ---------------- edge kernel: one wave per dst node, bf16 vectorized gathers ----------------
__global__ __launch_bounds__(256,3) void edge_kernel(
    const int* __restrict__ ei, const float* __restrict__ rij,
    const float* __restrict__ fij, const float* __restrict__ dij,
    const float* __restrict__ qg, const u16* __restrict__ kh,
    const u16* __restrict__ vh, const u16* __restrict__ vech,
    const short* __restrict__ wdkf, const short* __restrict__ wdvf,
    const float* __restrict__ bdk, const float* __restrict__ bdv,
    const int* __restrict__ offs, const int* __restrict__ perm,
    float* __restrict__ xagg, float* __restrict__ dvec)
{
  __shared__ float accs_x[4][256];
  __shared__ float accs_v[4][768];
  __shared__ float attn_s[4][16][8];
  __shared__ int   esrc_s[4][16];
  __shared__ float ecut_s[4][16];
  __shared__ float emask_s[4][16];
  __shared__ float edij_s[4][3][16];

  int tid  = threadIdx.x;
  int wv   = tid >> 6, lane = tid & 63;
  int ln15 = lane & 15, quad = lane >> 4;
  int n    = blockIdx.x*4 + wv;
  int rs = offs[n], re = offs[n+1];

  #pragma unroll
  for(int i=0;i<4;i++)  accs_x[wv][i*64 + lane] = 0.f;
  #pragma unroll
  for(int i=0;i<12;i++) accs_v[wv][i*64 + lane] = 0.f;

  // hoist q row + dk bias into registers (channel c = g*64 + 4*ln15 + p)
  float qreg[16], bkreg[16];
  #pragma unroll
  for(int g=0; g<4; g++){
    float4 t = *(const float4*)(qg + (size_t)n*H + g*64 + 4*ln15);
    qreg[g*4+0]=t.x; qreg[g*4+1]=t.y; qreg[g*4+2]=t.z; qreg[g*4+3]=t.w;
    float4 u = *(const float4*)(bdk + g*64 + 4*ln15);
    bkreg[g*4+0]=u.x; bkreg[g*4+1]=u.y; bkreg[g*4+2]=u.z; bkreg[g*4+3]=u.w;
  }

  for(int base = rs; base < re; base += 16){
    int idx = base + ln15;
    bool val = idx < re;
    int e = perm[val ? idx : rs];
    if(quad == 0){
      esrc_s[wv][ln15] = ei[e];
      float r = rij[e];
      float cu = 0.5f*(__cosf(r*0.6283185307f)+1.f);
      cu = (r < 5.f) ? cu : 0.f;
      ecut_s[wv][ln15]  = val ? cu : 0.f;
      emask_s[wv][ln15] = val ? 1.f : 0.f;
      edij_s[wv][0][ln15] = dij[e*3+0];
      edij_s[wv][1][ln15] = dij[e*3+1];
      edij_s[wv][2][ln15] = dij[e*3+2];
    }
    // A fragments from fp32 f_ij
    bfrag af0, af1;
    {
      const float* fr = fij + (size_t)e*64 + quad*8;
      float4 fa = *(const float4*)fr;
      float4 fb = *(const float4*)(fr+4);
      float4 fc = *(const float4*)(fr+32);
      float4 fd = *(const float4*)(fr+36);
      af0[0]=(short)f2bf(fa.x); af0[1]=(short)f2bf(fa.y); af0[2]=(short)f2bf(fa.z); af0[3]=(short)f2bf(fa.w);
      af0[4]=(short)f2bf(fb.x); af0[5]=(short)f2bf(fb.y); af0[6]=(short)f2bf(fb.z); af0[7]=(short)f2bf(fb.w);
      af1[0]=(short)f2bf(fc.x); af1[1]=(short)f2bf(fc.y); af1[2]=(short)f2bf(fc.z); af1[3]=(short)f2bf(fc.w);
      af1[4]=(short)f2bf(fd.x); af1[5]=(short)f2bf(fd.y); af1[6]=(short)f2bf(fd.z); af1[7]=(short)f2bf(fd.w);
    }
    int sns[4]; float mk[4];
    #pragma unroll
    for(int r=0;r<4;r++){
      int el = quad*4 + r;
      sns[r] = esrc_s[wv][el];
      mk[r]  = emask_s[wv][el];
    }

    // k gathers: ushort4 covers this lane's column in 4 subtiles of group g
    u16x4 kr[4][4];
    #pragma unroll
    for(int g=0;g<4;g++)
      #pragma unroll
      for(int r=0;r<4;r++)
        kr[g][r] = *(const u16x4*)(kh + (size_t)sns[r]*H + g*64 + 4*ln15);

    // ---- dk + per-head attention (group g = heads 2g, 2g+1) ----
    #pragma unroll
    for(int g=0;g<4;g++){
      float lgg[4] = {0.f,0.f,0.f,0.f};
      #pragma unroll
      for(int p=0;p<4;p++){
        const short* wp = wdkf + (g*4+p)*1024 + quad*128 + ln15*8;
        bfrag b0 = *(const bfrag*)wp;
        bfrag b1 = *(const bfrag*)(wp + 512);
        f32x4 acc = {0.f,0.f,0.f,0.f};
        acc = __builtin_amdgcn_mfma_f32_16x16x32_bf16(af0, b0, acc, 0,0,0);
        acc = __builtin_amdgcn_mfma_f32_16x16x32_bf16(af1, b1, acc, 0,0,0);
        float bias = bkreg[g*4+p], qv = qreg[g*4+p];
        #pragma unroll
        for(int r=0;r<4;r++){
          float dk = silu_f(acc[r] + bias);
          lgg[r] += dk * qv * bf2f(kr[g][r][p]);
        }
      }
      // reduce over 8 lanes -> per-head logit (lanes 0-7: head 2g, 8-15: head 2g+1)
      #pragma unroll
      for(int r=0;r<4;r++){
        lgg[r] += __shfl_xor(lgg[r],1,64);
        lgg[r] += __shfl_xor(lgg[r],2,64);
        lgg[r] += __shfl_xor(lgg[r],4,64);
      }
      if((ln15 & 7) == 0){
        int hh = 2*g + (ln15 >> 3);
        #pragma unroll
        for(int r=0;r<4;r++){
          int el = quad*4 + r;
          attn_s[wv][el][hh] = silu_f(lgg[r]) * ecut_s[wv][el];
        }
      }
    }

    // ---- dv + accumulate, per head ----
    #pragma unroll 1
    for(int h=0;h<8;h++){
      u16x2 vld[3][4], vcl[3][4];
      #pragma unroll
      for(int st=0;st<3;st++)
        #pragma unroll
        for(int r=0;r<4;r++)
          vld[st][r] = *(const u16x2*)(vh + (size_t)sns[r]*H3 + h*96 + st*32 + 2*ln15);
      #pragma unroll
      for(int d=0;d<3;d++)
        #pragma unroll
        for(int r=0;r<4;r++)
          vcl[d][r] = *(const u16x2*)(vech + (size_t)sns[r]*H3 + d*H + h*32 + 2*ln15);
      float bb[6];
      #pragma unroll
      for(int st=0;st<3;st++){
        float2 b2 = *(const float2*)(bdv + h*96 + st*32 + 2*ln15);
        bb[st*2] = b2.x; bb[st*2+1] = b2.y;
      }
      float at[4];
      #pragma unroll
      for(int r=0;r<4;r++) at[r] = attn_s[wv][quad*4+r][h];

      float v1v[2][4], vjv[2][4];
      float xmt[2] = {0.f, 0.f};
      #pragma unroll
      for(int st=0;st<3;st++){
        #pragma unroll
        for(int p=0;p<2;p++){
          const short* wp = wdvf + (h*6+st*2+p)*1024 + quad*128 + ln15*8;
          bfrag b0 = *(const bfrag*)wp;
          bfrag b1 = *(const bfrag*)(wp + 512);
          f32x4 acc = {0.f,0.f,0.f,0.f};
          acc = __builtin_amdgcn_mfma_f32_16x16x32_bf16(af0, b0, acc, 0,0,0);
          acc = __builtin_amdgcn_mfma_f32_16x16x32_bf16(af1, b1, acc, 0,0,0);
          float bias = bb[st*2+p];
          #pragma unroll
          for(int r=0;r<4;r++){
            float dvv = silu_f(acc[r] + bias) * mk[r];
            float vj = bf2f(vld[st][r][p]) * dvv;
            if(st == 0)      xmt[p]    += vj * at[r];
            else if(st == 1) v1v[p][r]  = vj;
            else             vjv[p][r]  = vj;
          }
        }
      }
      #pragma unroll
      for(int p=0;p<2;p++){
        xmt[p] += __shfl_xor(xmt[p],16,64);
        xmt[p] += __shfl_xor(xmt[p],32,64);
      }
      if(quad == 0){
        accs_x[wv][h*32 + 2*ln15 + 0] += xmt[0];
        accs_x[wv][h*32 + 2*ln15 + 1] += xmt[1];
      }
      #pragma unroll
      for(int d=0;d<3;d++){
        float t0 = 0.f, t1 = 0.f;
        #pragma unroll
        for(int r=0;r<4;r++){
          float dj = edij_s[wv][d][quad*4+r];
          t0 += bf2f(vcl[d][r][0]) * v1v[0][r] + dj * vjv[0][r];
          t1 += bf2f(vcl[d][r][1]) * v1v[1][r] + dj * vjv[1][r];
        }
        t0 += __shfl_xor(t0,16,64); t0 += __shfl_xor(t0,32,64);
        t1 += __shfl_xor(t1,16,64); t1 += __shfl_xor(t1,32,64);
        if(quad == 0){
          accs_v[wv][d*H + h*32 + 2*ln15 + 0] += t0;
          accs_v[wv][d*H + h*32 + 2*ln15 + 1] += t1;
        }
      }
    }
  }

  #pragma unroll
  for(int j=0;j<4;j++)  xagg[(size_t)n*H  + j*64 + lane] = accs_x[wv][j*64 + lane];
  #pragma unroll
  for(int j=0;j<12;j++) dvec[(size_t)n*H3 + j*64 + lane] = accs_v[wv][j*64 + lane];
}

// ---- epilogue ----
__global__ __launch_bounds__(256) void final_kernel(
    const float* __restrict__ ob, const float* __restrict__ vd,
    const float* __restrict__ vp3, float* __restrict__ out)
{
  int i = blockIdx.x*256 + threadIdx.x;
  int n = i >> 8, c = i & 255;
  float o1 = ob[(size_t)n*H3 + c];
  float o2 = ob[(size_t)n*H3 + 256 + c];
  float o3 = ob[(size_t)n*H3 + 512 + c];
  out[i] = vd[i]*o2 + o3;
  float* dvec = out + (size_t)NN*H;
  #pragma unroll
  for(int d=0;d<3;d++){
    dvec[(size_t)n*H3 + d*H + c] += vp3[(size_t)(3*n+d)*256 + c] * o1;
  }
}

extern "C" void kernel_launch(void* const* d_in, const int* in_sizes, int n_in,
                              void* d_out, int out_size, void* d_ws, size_t ws_size,
                              hipStream_t stream){
  (void)in_sizes; (void)n_in; (void)out_size; (void)ws_size;
  const float* x    = (const float*)d_in[0];
  const float* vec  = (const float*)d_in[1];
  const int*   ei   = (const int*)d_in[2];
  const float* rij  = (const float*)d_in[3];
  const float* fij  = (const float*)d_in[4];
  const float* dij  = (const float*)d_in[5];
  const float* ln_w = (const float*)d_in[6];
  const float* ln_b = (const float*)d_in[7];
  const float* Wq   = (const float*)d_in[8];
  const float* bq   = (const float*)d_in[9];
  const float* Wk   = (const float*)d_in[10];
  const float* bk   = (const float*)d_in[11];
  const float* Wv   = (const float*)d_in[12];
  const float* bv   = (const float*)d_in[13];
  const float* Wo   = (const float*)d_in[14];
  const float* bo   = (const float*)d_in[15];
  const float* Wvec = (const float*)d_in[16];
  const float* Wdk  = (const float*)d_in[17];
  const float* bdk  = (const float*)d_in[18];
  const float* Wdv  = (const float*)d_in[19];
  const float* bdv  = (const float*)d_in[20];
  float* out = (float*)d_out;
  float* ws  = (float*)d_ws;

  // workspace layout (float offsets), total ~320.4 MB
  float* qb   = ws;                    // [N,256]
  float* vd   = ws +  5120000;         // [N,256]
  float* xagg = ws + 10240000;         // [N,256]
  float* vp1  = ws + 15360000;         // [3N,256]  (also: xn before vec_proj; ob after edge)
  float* vp2  = ws + 30720000;         // [3N,256]
  float* vp3  = ws + 46080000;         // [3N,256]
  u16*   kh   = (u16*)(ws + 61440000); // [N,256] bf16
  u16*   vh   = (u16*)(ws + 64000000); // [N,768] bf16
  u16*   vech = (u16*)(ws + 71680000); // [N,768] bf16
  int* deg    = (int*)(ws + 79360000);
  int* offs   = deg + 20032;
  int* cursor = offs + 20032;
  int* perm   = cursor + 20032;
  short* wdkf = (short*)(perm + 640000);
  short* wdvf = wdkf + 16384;

  float* xn = vp1;                     // alias: dead before vec_proj writes vp1
  float* ob = vp1;                     // alias: vp1 dead after vecdot
  float* dvec = out + (size_t)NN*H;

  ln_kernel<<<20000, 256, 0, stream>>>(x, ln_w, ln_b, xn);
  gemm_node<0><<<dim3(313,4),  256, 0, stream>>>(xn, Wq, 256, bq, qb, nullptr, 0, 20000);
  gemm_node<1><<<dim3(313,4),  256, 0, stream>>>(xn, Wk, 256, bk, nullptr, kh, 0, 20000);
  gemm_node<1><<<dim3(313,12), 256, 0, stream>>>(xn, Wv, 768, bv, nullptr, vh, 0, 20000);

  hipMemsetAsync(deg,    0, 20000*sizeof(int), stream);
  hipMemsetAsync(cursor, 0, 20000*sizeof(int), stream);
  hist_kernel<<<2500, 256, 0, stream>>>(ei, deg);
  scan_kernel<<<1, 1024, 0, stream>>>(deg, offs);
  scatter_kernel<<<2500, 256, 0, stream>>>(ei, offs, cursor, perm);
  conv_wdk<<<64,  256, 0, stream>>>(Wdk, wdkf);
  conv_wdv<<<192, 256, 0, stream>>>(Wdv, wdvf);
  cvt_bf16<<<15000, 256, 0, stream>>>(vec, vech, 3840000);

  gemm_node<2><<<dim3(938,12), 256, 0, stream>>>(vec, Wvec, 768, nullptr, vp1, nullptr, 15360000L, 60000);
  vecdot_kernel<<<20000, 256, 0, stream>>>(vp1, vp2, vd);

  edge_kernel<<<5000, 256, 0, stream>>>(ei, rij, fij, dij, qb, kh, vh, vech,
                                        wdkf, wdvf, bdk, bdv, offs, perm,
                                        xagg, dvec);

  gemm_node<0><<<dim3(313,12), 256, 0, stream>>>(xagg, Wo, 768, bo, ob, nullptr, 0, 20000);
  final_kernel<<<20000, 256, 0, stream>>>(ob, vd, vp3, out);
}